// Round 1
// baseline (265.381 us; speedup 1.0000x reference)
//
#include <hip/hip_runtime.h>
#include <math.h>

#define NS 64
#define NV 16
#define IN_DIM 176      // 64 + 48 + 48 + 16
#define W_NUMEL 7936    // 80*64 + 96*16 + 48*16 + 32*16
#define OUT_DIM 176

// weight flat offsets per row
#define OFF_0E 0        // (80, 64)
#define OFF_1O 5120     // (96, 16)
#define OFF_1E 6656     // (48, 16)
#define OFF_0O 7424     // (32, 16)

__global__ __launch_bounds__(192)
void ftp_kernel(const float* __restrict__ in_,
                const float* __restrict__ sh,
                const float* __restrict__ weight,
                float* __restrict__ out)
{
    __shared__ float s_in[IN_DIM];
    __shared__ float s_sh4[4];
    __shared__ float s_o0e[80];
    __shared__ float s_o1o[96 * 3];
    __shared__ float s_o1e[48 * 3];
    __shared__ float s_o0o[32];

    const int row = blockIdx.x;
    const int t = threadIdx.x;
    const float* __restrict__ inr  = in_    + (size_t)row * IN_DIM;
    const float* __restrict__ wr   = weight + (size_t)row * W_NUMEL;
    float* __restrict__       outr = out    + (size_t)row * OUT_DIM;

    if (t < IN_DIM) s_in[t] = inr[t];
    if (t >= 176 && t < 180) s_sh4[t - 176] = sh[(size_t)row * 4 + (t - 176)];
    __syncthreads();

    const float sh0 = s_sh4[0];
    const float sh1_0 = s_sh4[1], sh1_1 = s_sh4[2], sh1_2 = s_sh4[3];
    const float sh1[3] = {sh1_0, sh1_1, sh1_2};
    const float inv_s3 = 0.5773502691896258f;   // 1/sqrt(3)
    const float inv_s2 = 0.7071067811865476f;   // 1/sqrt(2)

    // ---- Phase 1: intermediates into LDS (544 values) ----
    for (int j = t; j < 544; j += 192) {
        if (j < 80) {
            int i = j;
            float val;
            if (i < 64) {
                val = s_in[i] * sh0;
            } else {
                int v = i - 64;
                val = (s_in[64 + v*3 + 0] * sh1_0 +
                       s_in[64 + v*3 + 1] * sh1_1 +
                       s_in[64 + v*3 + 2] * sh1_2) * inv_s3;
            }
            s_o0e[i] = val;
        } else if (j < 368) {
            int jj = j - 80;
            int i = jj / 3, c = jj % 3;
            float val;
            if (i < 64) {
                val = s_in[i] * sh1[c];
            } else if (i < 80) {
                int v = i - 64;
                val = s_in[64 + v*3 + c] * sh0;
            } else {
                int v = i - 80;
                int c1 = (c + 1) % 3, c2 = (c + 2) % 3;
                // cross(x1e[v], sh1)[c]
                val = (s_in[112 + v*3 + c1] * sh1[c2] -
                       s_in[112 + v*3 + c2] * sh1[c1]) * inv_s2;
            }
            s_o1o[jj] = val;
        } else if (j < 512) {
            int jj = j - 368;
            int i = jj / 3, c = jj % 3;
            float val;
            if (i < 16) {
                int v = i;
                int c1 = (c + 1) % 3, c2 = (c + 2) % 3;
                // cross(x1o[v], sh1)[c]
                val = (s_in[64 + v*3 + c1] * sh1[c2] -
                       s_in[64 + v*3 + c2] * sh1[c1]) * inv_s2;
            } else if (i < 32) {
                int v = i - 16;
                val = s_in[112 + v*3 + c] * sh0;
            } else {
                int v = i - 32;
                val = s_in[160 + v] * sh1[c];
            }
            s_o1e[jj] = val;
        } else {
            int i = j - 512;
            float val;
            if (i < 16) {
                val = (s_in[112 + i*3 + 0] * sh1_0 +
                       s_in[112 + i*3 + 1] * sh1_1 +
                       s_in[112 + i*3 + 2] * sh1_2) * inv_s3;
            } else {
                val = s_in[160 + (i - 16)] * sh0;
            }
            s_o0o[i] = val;
        }
    }
    __syncthreads();

    // ---- Phase 2: per-output dot products over streamed weights ----
    // thread -> (weight base, stride, lds base/stride, count, out pos, norm)
    int count = 0, wbase = 0, wstride = 16;
    const float* lbase = s_o0e;
    int lstride = 1;
    int opos = -1;
    float norm = 1.0f;

    if (t < 64) {                       // y0e[o], o = t
        count = 80; wbase = OFF_0E + t; wstride = 64;
        lbase = s_o0e; lstride = 1;
        opos = t; norm = 0.11180339887498949f;           // 1/sqrt(80)
    } else if (t < 112) {               // y1o[o][c]
        int u = t - 64; int c = u / 16, o = u % 16;
        count = 96; wbase = OFF_1O + o;
        lbase = s_o1o + c; lstride = 3;
        opos = 64 + o*3 + c; norm = 0.10206207261596575f; // 1/sqrt(96)
    } else if (t < 128) {               // y1e[o][0]
        int o = t - 112;
        count = 48; wbase = OFF_1E + o;
        lbase = s_o1e + 0; lstride = 3;
        opos = 112 + o*3 + 0; norm = 0.14433756729740643f; // 1/sqrt(48)
    } else if (t < 160) {               // y1e[o][c], c = 1,2
        int u = t - 128; int c = 1 + u / 16, o = u % 16;
        count = 48; wbase = OFF_1E + o;
        lbase = s_o1e + c; lstride = 3;
        opos = 112 + o*3 + c; norm = 0.14433756729740643f;
    } else if (t < 176) {               // y0o[o]
        int o = t - 160;
        count = 32; wbase = OFF_0O + o;
        lbase = s_o0o; lstride = 1;
        opos = 160 + o; norm = 0.17677669529663687f;      // 1/sqrt(32)
    }

    float acc = 0.0f;
    for (int i = 0; i < count; ++i) {
        acc += wr[wbase + i * wstride] * lbase[i * lstride];
    }
    if (opos >= 0) outr[opos] = acc * norm;
}

extern "C" void kernel_launch(void* const* d_in, const int* in_sizes, int n_in,
                              void* d_out, int out_size, void* d_ws, size_t ws_size,
                              hipStream_t stream) {
    const float* in_    = (const float*)d_in[0];
    const float* sh     = (const float*)d_in[1];
    const float* weight = (const float*)d_in[2];
    float* out = (float*)d_out;
    const int E = in_sizes[0] / IN_DIM;

    ftp_kernel<<<E, 192, 0, stream>>>(in_, sh, weight, out);
}

// Round 2
// 98.853 us; speedup vs baseline: 2.6846x; 2.6846x over previous
//
#include <hip/hip_runtime.h>
#include <math.h>

#define NS 64
#define NV 16
#define IN_DIM 176      // 64 + 48 + 48 + 16
#define W_NUMEL 7936    // 80*64 + 96*16 + 48*16 + 32*16
#define OUT_DIM 176

// weight flat offsets per row (floats)
#define OFF_0E 0        // (80, 64)
#define OFF_1O 5120     // (96, 16)
#define OFF_1E 6656     // (48, 16)
#define OFF_0O 7424     // (32, 16)

__global__ __launch_bounds__(256)
void ftp_kernel(const float* __restrict__ in_,
                const float* __restrict__ sh,
                const float* __restrict__ weight,
                float* __restrict__ out)
{
    __shared__ float s_in[IN_DIM];
    __shared__ float s_sh4[4];
    __shared__ float s_o0e[80];
    __shared__ float s_o1o[96 * 3];
    __shared__ float s_o1e[48 * 3];
    __shared__ float s_o0o[32];

    const int row = blockIdx.x;
    const int t = threadIdx.x;
    const float* __restrict__ inr  = in_    + (size_t)row * IN_DIM;
    const float* __restrict__ wr   = weight + (size_t)row * W_NUMEL;
    float* __restrict__       outr = out    + (size_t)row * OUT_DIM;

    if (t < IN_DIM) s_in[t] = inr[t];
    if (t >= 176 && t < 180) s_sh4[t - 176] = sh[(size_t)row * 4 + (t - 176)];
    __syncthreads();

    const float sh0 = s_sh4[0];
    const float sh1_0 = s_sh4[1], sh1_1 = s_sh4[2], sh1_2 = s_sh4[3];
    const float sh1[3] = {sh1_0, sh1_1, sh1_2};
    const float inv_s3 = 0.5773502691896258f;   // 1/sqrt(3)
    const float inv_s2 = 0.7071067811865476f;   // 1/sqrt(2)

    // ---- Phase 1: intermediates into LDS (544 values) ----
    for (int j = t; j < 544; j += 256) {
        if (j < 80) {
            int i = j;
            float val;
            if (i < 64) {
                val = s_in[i] * sh0;
            } else {
                int v = i - 64;
                val = (s_in[64 + v*3 + 0] * sh1_0 +
                       s_in[64 + v*3 + 1] * sh1_1 +
                       s_in[64 + v*3 + 2] * sh1_2) * inv_s3;
            }
            s_o0e[i] = val;
        } else if (j < 368) {
            int jj = j - 80;
            int i = jj / 3, c = jj % 3;
            float val;
            if (i < 64) {
                val = s_in[i] * sh1[c];
            } else if (i < 80) {
                int v = i - 64;
                val = s_in[64 + v*3 + c] * sh0;
            } else {
                int v = i - 80;
                int c1 = (c + 1) % 3, c2 = (c + 2) % 3;
                val = (s_in[112 + v*3 + c1] * sh1[c2] -
                       s_in[112 + v*3 + c2] * sh1[c1]) * inv_s2;
            }
            s_o1o[jj] = val;
        } else if (j < 512) {
            int jj = j - 368;
            int i = jj / 3, c = jj % 3;
            float val;
            if (i < 16) {
                int v = i;
                int c1 = (c + 1) % 3, c2 = (c + 2) % 3;
                val = (s_in[64 + v*3 + c1] * sh1[c2] -
                       s_in[64 + v*3 + c2] * sh1[c1]) * inv_s2;
            } else if (i < 32) {
                int v = i - 16;
                val = s_in[112 + v*3 + c] * sh0;
            } else {
                int v = i - 32;
                val = s_in[160 + v] * sh1[c];
            }
            s_o1e[jj] = val;
        } else {
            int i = j - 512;
            float val;
            if (i < 16) {
                val = (s_in[112 + i*3 + 0] * sh1_0 +
                       s_in[112 + i*3 + 1] * sh1_1 +
                       s_in[112 + i*3 + 2] * sh1_2) * inv_s3;
            } else {
                val = s_in[160 + (i - 16)] * sh0;
            }
            s_o0o[i] = val;
        }
    }
    __syncthreads();

    // ---- Phase 2: wave-uniform, fully-unrolled float4 GEMV ----
    const int wave = t >> 6;
    const int l = t & 63;

    if (wave < 2) {
        // y0e: 80x64, this wave covers outputs [wave*32, wave*32+32)
        const int o4 = (wave << 3) + (l & 7);   // output quad index 0..15
        const int g  = l >> 3;                  // i-group 0..7
        float ax = 0.f, ay = 0.f, az = 0.f, aw = 0.f;
        #pragma unroll
        for (int k = 0; k < 10; ++k) {
            const int i = g + (k << 3);
            const float4 w4 = *reinterpret_cast<const float4*>(wr + OFF_0E + i*64 + 4*o4);
            const float s = s_o0e[i];
            ax += w4.x * s; ay += w4.y * s; az += w4.z * s; aw += w4.w * s;
        }
        #pragma unroll
        for (int m = 8; m <= 32; m <<= 1) {
            ax += __shfl_xor(ax, m);
            ay += __shfl_xor(ay, m);
            az += __shfl_xor(az, m);
            aw += __shfl_xor(aw, m);
        }
        if (g == 0) {
            const float n = 0.11180339887498949f;  // 1/sqrt(80)
            float4 r; r.x = ax*n; r.y = ay*n; r.z = az*n; r.w = aw*n;
            *reinterpret_cast<float4*>(outr + 4*o4) = r;
        }
    } else if (wave == 2) {
        // y1o: 96x16, 3 c-components share each weight column
        const int o4 = l & 3;                   // output quad 0..3
        const int g  = l >> 2;                  // i-group 0..15
        float a0x=0,a0y=0,a0z=0,a0w=0;
        float a1x=0,a1y=0,a1z=0,a1w=0;
        float a2x=0,a2y=0,a2z=0,a2w=0;
        #pragma unroll
        for (int k = 0; k < 6; ++k) {
            const int i = g + (k << 4);
            const float4 w4 = *reinterpret_cast<const float4*>(wr + OFF_1O + i*16 + 4*o4);
            const float s0 = s_o1o[i*3 + 0];
            const float s1 = s_o1o[i*3 + 1];
            const float s2 = s_o1o[i*3 + 2];
            a0x += w4.x*s0; a0y += w4.y*s0; a0z += w4.z*s0; a0w += w4.w*s0;
            a1x += w4.x*s1; a1y += w4.y*s1; a1z += w4.z*s1; a1w += w4.w*s1;
            a2x += w4.x*s2; a2y += w4.y*s2; a2z += w4.z*s2; a2w += w4.w*s2;
        }
        #pragma unroll
        for (int m = 4; m <= 32; m <<= 1) {
            a0x += __shfl_xor(a0x, m); a0y += __shfl_xor(a0y, m);
            a0z += __shfl_xor(a0z, m); a0w += __shfl_xor(a0w, m);
            a1x += __shfl_xor(a1x, m); a1y += __shfl_xor(a1y, m);
            a1z += __shfl_xor(a1z, m); a1w += __shfl_xor(a1w, m);
            a2x += __shfl_xor(a2x, m); a2y += __shfl_xor(a2y, m);
            a2z += __shfl_xor(a2z, m); a2w += __shfl_xor(a2w, m);
        }
        if (g == 0) {
            const float n = 0.10206207261596575f;  // 1/sqrt(96)
            const int ob = 4*o4;
            outr[64 + (ob+0)*3 + 0] = a0x*n; outr[64 + (ob+0)*3 + 1] = a1x*n; outr[64 + (ob+0)*3 + 2] = a2x*n;
            outr[64 + (ob+1)*3 + 0] = a0y*n; outr[64 + (ob+1)*3 + 1] = a1y*n; outr[64 + (ob+1)*3 + 2] = a2y*n;
            outr[64 + (ob+2)*3 + 0] = a0z*n; outr[64 + (ob+2)*3 + 1] = a1z*n; outr[64 + (ob+2)*3 + 2] = a2z*n;
            outr[64 + (ob+3)*3 + 0] = a0w*n; outr[64 + (ob+3)*3 + 1] = a1w*n; outr[64 + (ob+3)*3 + 2] = a2w*n;
        }
    } else {
        // y1e: 48x16
        {
            const int o4 = l & 3;
            const int g  = l >> 2;
            float a0x=0,a0y=0,a0z=0,a0w=0;
            float a1x=0,a1y=0,a1z=0,a1w=0;
            float a2x=0,a2y=0,a2z=0,a2w=0;
            #pragma unroll
            for (int k = 0; k < 3; ++k) {
                const int i = g + (k << 4);
                const float4 w4 = *reinterpret_cast<const float4*>(wr + OFF_1E + i*16 + 4*o4);
                const float s0 = s_o1e[i*3 + 0];
                const float s1 = s_o1e[i*3 + 1];
                const float s2 = s_o1e[i*3 + 2];
                a0x += w4.x*s0; a0y += w4.y*s0; a0z += w4.z*s0; a0w += w4.w*s0;
                a1x += w4.x*s1; a1y += w4.y*s1; a1z += w4.z*s1; a1w += w4.w*s1;
                a2x += w4.x*s2; a2y += w4.y*s2; a2z += w4.z*s2; a2w += w4.w*s2;
            }
            #pragma unroll
            for (int m = 4; m <= 32; m <<= 1) {
                a0x += __shfl_xor(a0x, m); a0y += __shfl_xor(a0y, m);
                a0z += __shfl_xor(a0z, m); a0w += __shfl_xor(a0w, m);
                a1x += __shfl_xor(a1x, m); a1y += __shfl_xor(a1y, m);
                a1z += __shfl_xor(a1z, m); a1w += __shfl_xor(a1w, m);
                a2x += __shfl_xor(a2x, m); a2y += __shfl_xor(a2y, m);
                a2z += __shfl_xor(a2z, m); a2w += __shfl_xor(a2w, m);
            }
            if (g == 0) {
                const float n = 0.14433756729740643f;  // 1/sqrt(48)
                const int ob = 4*o4;
                outr[112 + (ob+0)*3 + 0] = a0x*n; outr[112 + (ob+0)*3 + 1] = a1x*n; outr[112 + (ob+0)*3 + 2] = a2x*n;
                outr[112 + (ob+1)*3 + 0] = a0y*n; outr[112 + (ob+1)*3 + 1] = a1y*n; outr[112 + (ob+1)*3 + 2] = a2y*n;
                outr[112 + (ob+2)*3 + 0] = a0z*n; outr[112 + (ob+2)*3 + 1] = a1z*n; outr[112 + (ob+2)*3 + 2] = a2z*n;
                outr[112 + (ob+3)*3 + 0] = a0w*n; outr[112 + (ob+3)*3 + 1] = a1w*n; outr[112 + (ob+3)*3 + 2] = a2w*n;
            }
        }
        // y0o: 32x16
        {
            const int o4 = l & 3;
            const int g  = l >> 2;
            float ax = 0.f, ay = 0.f, az = 0.f, aw = 0.f;
            #pragma unroll
            for (int k = 0; k < 2; ++k) {
                const int i = g + (k << 4);
                const float4 w4 = *reinterpret_cast<const float4*>(wr + OFF_0O + i*16 + 4*o4);
                const float s = s_o0o[i];
                ax += w4.x * s; ay += w4.y * s; az += w4.z * s; aw += w4.w * s;
            }
            #pragma unroll
            for (int m = 4; m <= 32; m <<= 1) {
                ax += __shfl_xor(ax, m);
                ay += __shfl_xor(ay, m);
                az += __shfl_xor(az, m);
                aw += __shfl_xor(aw, m);
            }
            if (g == 0) {
                const float n = 0.17677669529663687f;  // 1/sqrt(32)
                float4 r; r.x = ax*n; r.y = ay*n; r.z = az*n; r.w = aw*n;
                *reinterpret_cast<float4*>(outr + 160 + 4*o4) = r;
            }
        }
    }
}

extern "C" void kernel_launch(void* const* d_in, const int* in_sizes, int n_in,
                              void* d_out, int out_size, void* d_ws, size_t ws_size,
                              hipStream_t stream) {
    const float* in_    = (const float*)d_in[0];
    const float* sh     = (const float*)d_in[1];
    const float* weight = (const float*)d_in[2];
    float* out = (float*)d_out;
    const int E = in_sizes[0] / IN_DIM;

    ftp_kernel<<<E, 256, 0, stream>>>(in_, sh, weight, out);
}

// Round 3
// 98.290 us; speedup vs baseline: 2.7000x; 1.0057x over previous
//
#include <hip/hip_runtime.h>

#define IN_DIM 176      // 64 + 48 + 48 + 16
#define W_NUMEL 7936    // 80*64 + 96*16 + 48*16 + 32*16
#define OUT_DIM 176

// weight flat offsets per row (floats)
#define OFF_0E 0        // (80, 64)
#define OFF_1O 5120     // (96, 16)
#define OFF_1E 6656     // (48, 16)
#define OFF_0O 7424     // (32, 16)

__global__ __launch_bounds__(256)
void ftp_kernel(const float* __restrict__ in_,
                const float* __restrict__ sh,
                const float* __restrict__ weight,
                float* __restrict__ out)
{
    // per-wave private input-row copies -> no __syncthreads needed anywhere
    __shared__ float s_in[4 * 192];

    const int row = blockIdx.x;
    const int t = threadIdx.x;
    const int wave = t >> 6;
    const int l = t & 63;

    const float* __restrict__ inr = in_    + (size_t)row * IN_DIM;
    const float* __restrict__ wr  = weight + (size_t)row * W_NUMEL;
    float* __restrict__       outr= out    + (size_t)row * OUT_DIM;
    const float* __restrict__ shr = sh     + (size_t)row * 4;

    float* s_my = &s_in[wave * 192];

    // issue input-row loads first (3 per lane, coalesced)
    const float a0 = inr[l];
    const float a1 = inr[64 + l];
    const float a2 = (l < 48) ? inr[128 + l] : 0.0f;

    // sh is wave-uniform (row from blockIdx) -> scalar loads
    const float sh0   = shr[0];
    const float sh1_0 = shr[1], sh1_1 = shr[2], sh1_2 = shr[3];

    const float inv_s3 = 0.5773502691896258f;   // 1/sqrt(3)
    const float inv_s2 = 0.7071067811865476f;   // 1/sqrt(2)

#define STAGE_AND_WAIT()                                        \
    do {                                                        \
        s_my[l] = a0; s_my[64 + l] = a1;                        \
        if (l < 48) s_my[128 + l] = a2;                         \
        __builtin_amdgcn_wave_barrier();                        \
        asm volatile("s_waitcnt lgkmcnt(0)" ::: "memory");      \
        __builtin_amdgcn_sched_barrier(0);                      \
    } while (0)

    if (wave < 2) {
        // ---- y0e: 80x64. outputs [wave*32, wave*32+32) ----
        const int o4 = (wave << 3) + (l & 7);   // output quad 0..15
        const int g  = l >> 3;                  // i-group 0..7
        float4 w[10];
        #pragma unroll
        for (int k = 0; k < 10; ++k)
            w[k] = *reinterpret_cast<const float4*>(wr + OFF_0E + (g + (k << 3)) * 64 + 4 * o4);

        STAGE_AND_WAIT();

        float s[10];
        #pragma unroll
        for (int k = 0; k < 8; ++k) s[k] = s_my[g + (k << 3)] * sh0;
        s[8] = (s_my[64 + 3*g] * sh1_0 + s_my[65 + 3*g] * sh1_1 + s_my[66 + 3*g] * sh1_2) * inv_s3;
        s[9] = (s_my[88 + 3*g] * sh1_0 + s_my[89 + 3*g] * sh1_1 + s_my[90 + 3*g] * sh1_2) * inv_s3;

        float ax = 0.f, ay = 0.f, az = 0.f, aw = 0.f;
        #pragma unroll
        for (int k = 0; k < 10; ++k) {
            ax += w[k].x * s[k]; ay += w[k].y * s[k];
            az += w[k].z * s[k]; aw += w[k].w * s[k];
        }
        #pragma unroll
        for (int m = 8; m <= 32; m <<= 1) {
            ax += __shfl_xor(ax, m); ay += __shfl_xor(ay, m);
            az += __shfl_xor(az, m); aw += __shfl_xor(aw, m);
        }
        if (g == 0) {
            const float n = 0.11180339887498949f;  // 1/sqrt(80)
            float4 r; r.x = ax*n; r.y = ay*n; r.z = az*n; r.w = aw*n;
            *reinterpret_cast<float4*>(outr + 4*o4) = r;
        }
    } else if (wave == 2) {
        // ---- y1o: 96x16 ----
        const int o4 = l & 3;                   // output quad 0..3
        const int g  = l >> 2;                  // i-group 0..15
        float4 w[6];
        #pragma unroll
        for (int k = 0; k < 6; ++k)
            w[k] = *reinterpret_cast<const float4*>(wr + OFF_1O + (g + (k << 4)) * 16 + 4 * o4);

        STAGE_AND_WAIT();

        float s0[6], s1[6], s2[6];
        #pragma unroll
        for (int k = 0; k < 4; ++k) {
            const float x = s_my[g + (k << 4)];
            s0[k] = x * sh1_0; s1[k] = x * sh1_1; s2[k] = x * sh1_2;
        }
        s0[4] = s_my[64 + 3*g] * sh0;
        s1[4] = s_my[65 + 3*g] * sh0;
        s2[4] = s_my[66 + 3*g] * sh0;
        {
            const float e0 = s_my[112 + 3*g], e1 = s_my[113 + 3*g], e2 = s_my[114 + 3*g];
            s0[5] = (e1 * sh1_2 - e2 * sh1_1) * inv_s2;
            s1[5] = (e2 * sh1_0 - e0 * sh1_2) * inv_s2;
            s2[5] = (e0 * sh1_1 - e1 * sh1_0) * inv_s2;
        }

        float a0x=0,a0y=0,a0z=0,a0w=0;
        float a1x=0,a1y=0,a1z=0,a1w=0;
        float a2x=0,a2y=0,a2z=0,a2w=0;
        #pragma unroll
        for (int k = 0; k < 6; ++k) {
            a0x += w[k].x*s0[k]; a0y += w[k].y*s0[k]; a0z += w[k].z*s0[k]; a0w += w[k].w*s0[k];
            a1x += w[k].x*s1[k]; a1y += w[k].y*s1[k]; a1z += w[k].z*s1[k]; a1w += w[k].w*s1[k];
            a2x += w[k].x*s2[k]; a2y += w[k].y*s2[k]; a2z += w[k].z*s2[k]; a2w += w[k].w*s2[k];
        }
        #pragma unroll
        for (int m = 4; m <= 32; m <<= 1) {
            a0x += __shfl_xor(a0x, m); a0y += __shfl_xor(a0y, m);
            a0z += __shfl_xor(a0z, m); a0w += __shfl_xor(a0w, m);
            a1x += __shfl_xor(a1x, m); a1y += __shfl_xor(a1y, m);
            a1z += __shfl_xor(a1z, m); a1w += __shfl_xor(a1w, m);
            a2x += __shfl_xor(a2x, m); a2y += __shfl_xor(a2y, m);
            a2z += __shfl_xor(a2z, m); a2w += __shfl_xor(a2w, m);
        }
        if (g == 0) {
            const float n = 0.10206207261596575f;  // 1/sqrt(96)
            const int ob = 4*o4;
            outr[64 + (ob+0)*3 + 0] = a0x*n; outr[64 + (ob+0)*3 + 1] = a1x*n; outr[64 + (ob+0)*3 + 2] = a2x*n;
            outr[64 + (ob+1)*3 + 0] = a0y*n; outr[64 + (ob+1)*3 + 1] = a1y*n; outr[64 + (ob+1)*3 + 2] = a2y*n;
            outr[64 + (ob+2)*3 + 0] = a0z*n; outr[64 + (ob+2)*3 + 1] = a1z*n; outr[64 + (ob+2)*3 + 2] = a2z*n;
            outr[64 + (ob+3)*3 + 0] = a0w*n; outr[64 + (ob+3)*3 + 1] = a1w*n; outr[64 + (ob+3)*3 + 2] = a2w*n;
        }
    } else {
        // ---- y1e: 48x16  then  y0o: 32x16 ----
        const int o4 = l & 3;
        const int g  = l >> 2;
        float4 wa[3], wb[2];
        #pragma unroll
        for (int k = 0; k < 3; ++k)
            wa[k] = *reinterpret_cast<const float4*>(wr + OFF_1E + (g + (k << 4)) * 16 + 4 * o4);
        #pragma unroll
        for (int k = 0; k < 2; ++k)
            wb[k] = *reinterpret_cast<const float4*>(wr + OFF_0O + (g + (k << 4)) * 16 + 4 * o4);

        STAGE_AND_WAIT();

        // y1e intermediates
        float s0[3], s1[3], s2[3];
        {
            const float o0 = s_my[64 + 3*g], o1 = s_my[65 + 3*g], o2 = s_my[66 + 3*g];
            s0[0] = (o1 * sh1_2 - o2 * sh1_1) * inv_s2;
            s1[0] = (o2 * sh1_0 - o0 * sh1_2) * inv_s2;
            s2[0] = (o0 * sh1_1 - o1 * sh1_0) * inv_s2;
        }
        const float e0 = s_my[112 + 3*g], e1 = s_my[113 + 3*g], e2 = s_my[114 + 3*g];
        s0[1] = e0 * sh0; s1[1] = e1 * sh0; s2[1] = e2 * sh0;
        {
            const float x = s_my[160 + g];
            s0[2] = x * sh1_0; s1[2] = x * sh1_1; s2[2] = x * sh1_2;
        }

        float a0x=0,a0y=0,a0z=0,a0w=0;
        float a1x=0,a1y=0,a1z=0,a1w=0;
        float a2x=0,a2y=0,a2z=0,a2w=0;
        #pragma unroll
        for (int k = 0; k < 3; ++k) {
            a0x += wa[k].x*s0[k]; a0y += wa[k].y*s0[k]; a0z += wa[k].z*s0[k]; a0w += wa[k].w*s0[k];
            a1x += wa[k].x*s1[k]; a1y += wa[k].y*s1[k]; a1z += wa[k].z*s1[k]; a1w += wa[k].w*s1[k];
            a2x += wa[k].x*s2[k]; a2y += wa[k].y*s2[k]; a2z += wa[k].z*s2[k]; a2w += wa[k].w*s2[k];
        }
        // y0o intermediates + accum (independent chain, overlaps)
        float sb0 = (e0 * sh1_0 + e1 * sh1_1 + e2 * sh1_2) * inv_s3;
        float sb1 = s_my[160 + g] * sh0;
        float bx = wb[0].x*sb0 + wb[1].x*sb1;
        float by = wb[0].y*sb0 + wb[1].y*sb1;
        float bz = wb[0].z*sb0 + wb[1].z*sb1;
        float bw = wb[0].w*sb0 + wb[1].w*sb1;

        #pragma unroll
        for (int m = 4; m <= 32; m <<= 1) {
            a0x += __shfl_xor(a0x, m); a0y += __shfl_xor(a0y, m);
            a0z += __shfl_xor(a0z, m); a0w += __shfl_xor(a0w, m);
            a1x += __shfl_xor(a1x, m); a1y += __shfl_xor(a1y, m);
            a1z += __shfl_xor(a1z, m); a1w += __shfl_xor(a1w, m);
            a2x += __shfl_xor(a2x, m); a2y += __shfl_xor(a2y, m);
            a2z += __shfl_xor(a2z, m); a2w += __shfl_xor(a2w, m);
            bx  += __shfl_xor(bx,  m); by  += __shfl_xor(by,  m);
            bz  += __shfl_xor(bz,  m); bw  += __shfl_xor(bw,  m);
        }
        if (g == 0) {
            const float n48 = 0.14433756729740643f;  // 1/sqrt(48)
            const int ob = 4*o4;
            outr[112 + (ob+0)*3 + 0] = a0x*n48; outr[112 + (ob+0)*3 + 1] = a1x*n48; outr[112 + (ob+0)*3 + 2] = a2x*n48;
            outr[112 + (ob+1)*3 + 0] = a0y*n48; outr[112 + (ob+1)*3 + 1] = a1y*n48; outr[112 + (ob+1)*3 + 2] = a2y*n48;
            outr[112 + (ob+2)*3 + 0] = a0z*n48; outr[112 + (ob+2)*3 + 1] = a1z*n48; outr[112 + (ob+2)*3 + 2] = a2z*n48;
            outr[112 + (ob+3)*3 + 0] = a0w*n48; outr[112 + (ob+3)*3 + 1] = a1w*n48; outr[112 + (ob+3)*3 + 2] = a2w*n48;

            const float n32 = 0.17677669529663687f;  // 1/sqrt(32)
            float4 r; r.x = bx*n32; r.y = by*n32; r.z = bz*n32; r.w = bw*n32;
            *reinterpret_cast<float4*>(outr + 160 + 4*o4) = r;
        }
    }
#undef STAGE_AND_WAIT
}

extern "C" void kernel_launch(void* const* d_in, const int* in_sizes, int n_in,
                              void* d_out, int out_size, void* d_ws, size_t ws_size,
                              hipStream_t stream) {
    const float* in_    = (const float*)d_in[0];
    const float* sh     = (const float*)d_in[1];
    const float* weight = (const float*)d_in[2];
    float* out = (float*)d_out;
    const int E = in_sizes[0] / IN_DIM;

    ftp_kernel<<<E, 256, 0, stream>>>(in_, sh, weight, out);
}

// Round 4
// 98.204 us; speedup vs baseline: 2.7023x; 1.0009x over previous
//
#include <hip/hip_runtime.h>

#define IN_DIM 176      // 64 + 48 + 48 + 16
#define W_NUMEL 7936    // 80*64 + 96*16 + 48*16 + 32*16
#define OUT_DIM 176

// weight flat offsets per row (floats)
#define OFF_0E 0        // (80, 64)
#define OFF_1O 5120     // (96, 16)
#define OFF_1E 6656     // (48, 16)
#define OFF_0O 7424     // (32, 16)

// ---------------- load helpers (issue only, no waits) ----------------

__device__ __forceinline__ void load_y0e(const float* __restrict__ wr, int l, int half, float4 w[10]) {
    const int o4 = (half << 3) + (l & 7);
    const int g  = l >> 3;
    #pragma unroll
    for (int k = 0; k < 10; ++k)
        w[k] = *reinterpret_cast<const float4*>(wr + OFF_0E + (g + (k << 3)) * 64 + 4 * o4);
}

__device__ __forceinline__ void load_y1o(const float* __restrict__ wr, int l, float4 w[6]) {
    const int o4 = l & 3;
    const int g  = l >> 2;
    #pragma unroll
    for (int k = 0; k < 6; ++k)
        w[k] = *reinterpret_cast<const float4*>(wr + OFF_1O + (g + (k << 4)) * 16 + 4 * o4);
}

__device__ __forceinline__ void load_y1eo(const float* __restrict__ wr, int l, float4 wa[3], float4 wb[2]) {
    const int o4 = l & 3;
    const int g  = l >> 2;
    #pragma unroll
    for (int k = 0; k < 3; ++k)
        wa[k] = *reinterpret_cast<const float4*>(wr + OFF_1E + (g + (k << 4)) * 16 + 4 * o4);
    #pragma unroll
    for (int k = 0; k < 2; ++k)
        wb[k] = *reinterpret_cast<const float4*>(wr + OFF_0O + (g + (k << 4)) * 16 + 4 * o4);
}

// ---------------- compute helpers (consume LDS row + weight regs) ----------------

__device__ __forceinline__ void comp_y0e(const float* __restrict__ s_row, const float4 w[10],
                                         int l, int half,
                                         float sh0, float sx, float sy, float sz,
                                         float* __restrict__ outr, bool valid) {
    const int o4 = (half << 3) + (l & 7);
    const int g  = l >> 3;
    const float inv_s3 = 0.5773502691896258f;
    float s[10];
    #pragma unroll
    for (int k = 0; k < 8; ++k) s[k] = s_row[g + (k << 3)] * sh0;
    s[8] = (s_row[64 + 3*g] * sx + s_row[65 + 3*g] * sy + s_row[66 + 3*g] * sz) * inv_s3;
    s[9] = (s_row[88 + 3*g] * sx + s_row[89 + 3*g] * sy + s_row[90 + 3*g] * sz) * inv_s3;

    float ax = 0.f, ay = 0.f, az = 0.f, aw = 0.f;
    #pragma unroll
    for (int k = 0; k < 10; ++k) {
        ax += w[k].x * s[k]; ay += w[k].y * s[k];
        az += w[k].z * s[k]; aw += w[k].w * s[k];
    }
    #pragma unroll
    for (int m = 8; m <= 32; m <<= 1) {
        ax += __shfl_xor(ax, m); ay += __shfl_xor(ay, m);
        az += __shfl_xor(az, m); aw += __shfl_xor(aw, m);
    }
    if (g == 0 && valid) {
        const float n = 0.11180339887498949f;  // 1/sqrt(80)
        float4 r; r.x = ax*n; r.y = ay*n; r.z = az*n; r.w = aw*n;
        *reinterpret_cast<float4*>(outr + 4*o4) = r;
    }
}

__device__ __forceinline__ void comp_y1o(const float* __restrict__ s_row, const float4 w[6],
                                         int l,
                                         float sh0, float sx, float sy, float sz,
                                         float* __restrict__ outr, bool valid) {
    const int o4 = l & 3;
    const int g  = l >> 2;
    const float inv_s2 = 0.7071067811865476f;
    float s0[6], s1[6], s2[6];
    #pragma unroll
    for (int k = 0; k < 4; ++k) {
        const float x = s_row[g + (k << 4)];
        s0[k] = x * sx; s1[k] = x * sy; s2[k] = x * sz;
    }
    s0[4] = s_row[64 + 3*g] * sh0;
    s1[4] = s_row[65 + 3*g] * sh0;
    s2[4] = s_row[66 + 3*g] * sh0;
    {
        const float e0 = s_row[112 + 3*g], e1 = s_row[113 + 3*g], e2 = s_row[114 + 3*g];
        s0[5] = (e1 * sz - e2 * sy) * inv_s2;
        s1[5] = (e2 * sx - e0 * sz) * inv_s2;
        s2[5] = (e0 * sy - e1 * sx) * inv_s2;
    }
    float a0x=0,a0y=0,a0z=0,a0w=0;
    float a1x=0,a1y=0,a1z=0,a1w=0;
    float a2x=0,a2y=0,a2z=0,a2w=0;
    #pragma unroll
    for (int k = 0; k < 6; ++k) {
        a0x += w[k].x*s0[k]; a0y += w[k].y*s0[k]; a0z += w[k].z*s0[k]; a0w += w[k].w*s0[k];
        a1x += w[k].x*s1[k]; a1y += w[k].y*s1[k]; a1z += w[k].z*s1[k]; a1w += w[k].w*s1[k];
        a2x += w[k].x*s2[k]; a2y += w[k].y*s2[k]; a2z += w[k].z*s2[k]; a2w += w[k].w*s2[k];
    }
    #pragma unroll
    for (int m = 4; m <= 32; m <<= 1) {
        a0x += __shfl_xor(a0x, m); a0y += __shfl_xor(a0y, m);
        a0z += __shfl_xor(a0z, m); a0w += __shfl_xor(a0w, m);
        a1x += __shfl_xor(a1x, m); a1y += __shfl_xor(a1y, m);
        a1z += __shfl_xor(a1z, m); a1w += __shfl_xor(a1w, m);
        a2x += __shfl_xor(a2x, m); a2y += __shfl_xor(a2y, m);
        a2z += __shfl_xor(a2z, m); a2w += __shfl_xor(a2w, m);
    }
    if (g == 0 && valid) {
        const float n = 0.10206207261596575f;  // 1/sqrt(96)
        const int ob = 4*o4;
        outr[64 + (ob+0)*3 + 0] = a0x*n; outr[64 + (ob+0)*3 + 1] = a1x*n; outr[64 + (ob+0)*3 + 2] = a2x*n;
        outr[64 + (ob+1)*3 + 0] = a0y*n; outr[64 + (ob+1)*3 + 1] = a1y*n; outr[64 + (ob+1)*3 + 2] = a2y*n;
        outr[64 + (ob+2)*3 + 0] = a0z*n; outr[64 + (ob+2)*3 + 1] = a1z*n; outr[64 + (ob+2)*3 + 2] = a2z*n;
        outr[64 + (ob+3)*3 + 0] = a0w*n; outr[64 + (ob+3)*3 + 1] = a1w*n; outr[64 + (ob+3)*3 + 2] = a2w*n;
    }
}

__device__ __forceinline__ void comp_y1eo(const float* __restrict__ s_row,
                                          const float4 wa[3], const float4 wb[2],
                                          int l,
                                          float sh0, float sx, float sy, float sz,
                                          float* __restrict__ outr, bool valid) {
    const int o4 = l & 3;
    const int g  = l >> 2;
    const float inv_s2 = 0.7071067811865476f;
    const float inv_s3 = 0.5773502691896258f;

    float s0[3], s1[3], s2[3];
    {
        const float o0 = s_row[64 + 3*g], o1 = s_row[65 + 3*g], o2 = s_row[66 + 3*g];
        s0[0] = (o1 * sz - o2 * sy) * inv_s2;
        s1[0] = (o2 * sx - o0 * sz) * inv_s2;
        s2[0] = (o0 * sy - o1 * sx) * inv_s2;
    }
    const float e0 = s_row[112 + 3*g], e1 = s_row[113 + 3*g], e2 = s_row[114 + 3*g];
    s0[1] = e0 * sh0; s1[1] = e1 * sh0; s2[1] = e2 * sh0;
    const float xo = s_row[160 + g];
    s0[2] = xo * sx; s1[2] = xo * sy; s2[2] = xo * sz;

    float a0x=0,a0y=0,a0z=0,a0w=0;
    float a1x=0,a1y=0,a1z=0,a1w=0;
    float a2x=0,a2y=0,a2z=0,a2w=0;
    #pragma unroll
    for (int k = 0; k < 3; ++k) {
        a0x += wa[k].x*s0[k]; a0y += wa[k].y*s0[k]; a0z += wa[k].z*s0[k]; a0w += wa[k].w*s0[k];
        a1x += wa[k].x*s1[k]; a1y += wa[k].y*s1[k]; a1z += wa[k].z*s1[k]; a1w += wa[k].w*s1[k];
        a2x += wa[k].x*s2[k]; a2y += wa[k].y*s2[k]; a2z += wa[k].z*s2[k]; a2w += wa[k].w*s2[k];
    }
    float sb0 = (e0 * sx + e1 * sy + e2 * sz) * inv_s3;
    float sb1 = xo * sh0;
    float bx = wb[0].x*sb0 + wb[1].x*sb1;
    float by = wb[0].y*sb0 + wb[1].y*sb1;
    float bz = wb[0].z*sb0 + wb[1].z*sb1;
    float bw = wb[0].w*sb0 + wb[1].w*sb1;

    #pragma unroll
    for (int m = 4; m <= 32; m <<= 1) {
        a0x += __shfl_xor(a0x, m); a0y += __shfl_xor(a0y, m);
        a0z += __shfl_xor(a0z, m); a0w += __shfl_xor(a0w, m);
        a1x += __shfl_xor(a1x, m); a1y += __shfl_xor(a1y, m);
        a1z += __shfl_xor(a1z, m); a1w += __shfl_xor(a1w, m);
        a2x += __shfl_xor(a2x, m); a2y += __shfl_xor(a2y, m);
        a2z += __shfl_xor(a2z, m); a2w += __shfl_xor(a2w, m);
        bx  += __shfl_xor(bx,  m); by  += __shfl_xor(by,  m);
        bz  += __shfl_xor(bz,  m); bw  += __shfl_xor(bw,  m);
    }
    if (g == 0 && valid) {
        const float n48 = 0.14433756729740643f;  // 1/sqrt(48)
        const int ob = 4*o4;
        outr[112 + (ob+0)*3 + 0] = a0x*n48; outr[112 + (ob+0)*3 + 1] = a1x*n48; outr[112 + (ob+0)*3 + 2] = a2x*n48;
        outr[112 + (ob+1)*3 + 0] = a0y*n48; outr[112 + (ob+1)*3 + 1] = a1y*n48; outr[112 + (ob+1)*3 + 2] = a2y*n48;
        outr[112 + (ob+2)*3 + 0] = a0z*n48; outr[112 + (ob+2)*3 + 1] = a1z*n48; outr[112 + (ob+2)*3 + 2] = a2z*n48;
        outr[112 + (ob+3)*3 + 0] = a0w*n48; outr[112 + (ob+3)*3 + 1] = a1w*n48; outr[112 + (ob+3)*3 + 2] = a2w*n48;

        const float n32 = 0.17677669529663687f;  // 1/sqrt(32)
        float4 r; r.x = bx*n32; r.y = by*n32; r.z = bz*n32; r.w = bw*n32;
        *reinterpret_cast<float4*>(outr + 160 + 4*o4) = r;
    }
}

// ---------------- kernel: 2 rows/block, role-swapped waves (balanced 15-16 f4 loads/lane) ----------------

__global__ __launch_bounds__(256, 4)
void ftp_kernel(const float* __restrict__ in_,
                const float* __restrict__ sh,
                const float* __restrict__ weight,
                float* __restrict__ out,
                int E)
{
    __shared__ float s_in[4][2][192];

    const int bid = blockIdx.x;
    const int t = threadIdx.x;
    const int wave = t >> 6;
    const int l = t & 63;

    const int r0 = 2 * bid;
    const int r1 = 2 * bid + 1;
    const bool v1 = (r1 < E);
    const int r1c = v1 ? r1 : r0;   // clamped for safe loads

    const float* __restrict__ in0 = in_ + (size_t)r0 * IN_DIM;
    const float* __restrict__ in1 = in_ + (size_t)r1c * IN_DIM;
    const float* __restrict__ wr0 = weight + (size_t)r0 * W_NUMEL;
    const float* __restrict__ wr1 = weight + (size_t)r1c * W_NUMEL;
    float* __restrict__ out0 = out + (size_t)r0 * OUT_DIM;
    float* __restrict__ out1 = out + (size_t)r1c * OUT_DIM;

    // issue input-row loads first (6 scalar loads/lane, coalesced)
    const float a0 = in0[l];
    const float a1 = in0[64 + l];
    const float a2 = (l < 48) ? in0[128 + l] : 0.0f;
    const float b0 = in1[l];
    const float b1 = in1[64 + l];
    const float b2 = (l < 48) ? in1[128 + l] : 0.0f;

    // sh (wave-uniform scalar loads)
    const float* shr0 = sh + (size_t)r0 * 4;
    const float* shr1 = sh + (size_t)r1c * 4;
    const float p0 = shr0[0], px = shr0[1], py = shr0[2], pz = shr0[3];
    const float q0 = shr1[0], qx = shr1[1], qy = shr1[2], qz = shr1[3];

    float* sA = &s_in[wave][0][0];
    float* sB = &s_in[wave][1][0];

#define STAGE_AND_WAIT()                                        \
    do {                                                        \
        sA[l] = a0; sA[64 + l] = a1; if (l < 48) sA[128 + l] = a2; \
        sB[l] = b0; sB[64 + l] = b1; if (l < 48) sB[128 + l] = b2; \
        __builtin_amdgcn_wave_barrier();                        \
        asm volatile("s_waitcnt lgkmcnt(0)" ::: "memory");      \
        __builtin_amdgcn_sched_barrier(0);                      \
    } while (0)

    if (wave == 0) {
        float4 wA[10]; load_y0e(wr0, l, 0, wA);
        float4 wB[6];  load_y1o(wr1, l, wB);
        STAGE_AND_WAIT();
        comp_y0e(sA, wA, l, 0, p0, px, py, pz, out0, true);
        comp_y1o(sB, wB, l, q0, qx, qy, qz, out1, v1);
    } else if (wave == 1) {
        float4 wA[10]; load_y0e(wr0, l, 1, wA);
        float4 wa[3], wb[2]; load_y1eo(wr1, l, wa, wb);
        STAGE_AND_WAIT();
        comp_y0e(sA, wA, l, 1, p0, px, py, pz, out0, true);
        comp_y1eo(sB, wa, wb, l, q0, qx, qy, qz, out1, v1);
    } else if (wave == 2) {
        float4 wA[6];  load_y1o(wr0, l, wA);
        float4 wB[10]; load_y0e(wr1, l, 0, wB);
        STAGE_AND_WAIT();
        comp_y1o(sA, wA, l, p0, px, py, pz, out0, true);
        comp_y0e(sB, wB, l, 0, q0, qx, qy, qz, out1, v1);
    } else {
        float4 wa[3], wb[2]; load_y1eo(wr0, l, wa, wb);
        float4 wB[10]; load_y0e(wr1, l, 1, wB);
        STAGE_AND_WAIT();
        comp_y1eo(sA, wa, wb, l, p0, px, py, pz, out0, true);
        comp_y0e(sB, wB, l, 1, q0, qx, qy, qz, out1, v1);
    }
#undef STAGE_AND_WAIT
}

extern "C" void kernel_launch(void* const* d_in, const int* in_sizes, int n_in,
                              void* d_out, int out_size, void* d_ws, size_t ws_size,
                              hipStream_t stream) {
    const float* in_    = (const float*)d_in[0];
    const float* sh     = (const float*)d_in[1];
    const float* weight = (const float*)d_in[2];
    float* out = (float*)d_out;
    const int E = in_sizes[0] / IN_DIM;
    const int nblocks = (E + 1) / 2;

    ftp_kernel<<<nblocks, 256, 0, stream>>>(in_, sh, weight, out, E);
}

// Round 6
// 88.770 us; speedup vs baseline: 2.9895x; 1.1063x over previous
//
#include <hip/hip_runtime.h>

#define IN_DIM 176      // 64 + 48 + 48 + 16
#define W_NUMEL 7936    // 80*64 + 96*16 + 48*16 + 32*16
#define OUT_DIM 176

// weight flat offsets per row (floats)
#define OFF_0E 0        // (80, 64)
#define OFF_1O 5120     // (96, 16)
#define OFF_1E 6656     // (48, 16)
#define OFF_0O 7424     // (32, 16)

typedef float vfloat4 __attribute__((ext_vector_type(4)));

// non-temporal float4 load: weights are read exactly once, ever
__device__ __forceinline__ float4 ldnt4(const float* p) {
    vfloat4 v = __builtin_nontemporal_load(reinterpret_cast<const vfloat4*>(p));
    float4 r; r.x = v.x; r.y = v.y; r.z = v.z; r.w = v.w;
    return r;
}

// ---------------- load helpers (issue only, no waits) ----------------

__device__ __forceinline__ void load_y0e(const float* __restrict__ wr, int l, int half, float4 w[10]) {
    const int o4 = (half << 3) + (l & 7);
    const int g  = l >> 3;
    #pragma unroll
    for (int k = 0; k < 10; ++k)
        w[k] = ldnt4(wr + OFF_0E + (g + (k << 3)) * 64 + 4 * o4);
}

__device__ __forceinline__ void load_y1o(const float* __restrict__ wr, int l, float4 w[6]) {
    const int o4 = l & 3;
    const int g  = l >> 2;
    #pragma unroll
    for (int k = 0; k < 6; ++k)
        w[k] = ldnt4(wr + OFF_1O + (g + (k << 4)) * 16 + 4 * o4);
}

__device__ __forceinline__ void load_y1eo(const float* __restrict__ wr, int l, float4 wa[3], float4 wb[2]) {
    const int o4 = l & 3;
    const int g  = l >> 2;
    #pragma unroll
    for (int k = 0; k < 3; ++k)
        wa[k] = ldnt4(wr + OFF_1E + (g + (k << 4)) * 16 + 4 * o4);
    #pragma unroll
    for (int k = 0; k < 2; ++k)
        wb[k] = ldnt4(wr + OFF_0O + (g + (k << 4)) * 16 + 4 * o4);
}

// ---------------- compute helpers (consume LDS row + weight regs) ----------------

__device__ __forceinline__ void comp_y0e(const float* __restrict__ s_row, const float4 w[10],
                                         int l, int half,
                                         float sh0, float sx, float sy, float sz,
                                         float* __restrict__ outr, bool valid) {
    const int o4 = (half << 3) + (l & 7);
    const int g  = l >> 3;
    const float inv_s3 = 0.5773502691896258f;
    float s[10];
    #pragma unroll
    for (int k = 0; k < 8; ++k) s[k] = s_row[g + (k << 3)] * sh0;
    s[8] = (s_row[64 + 3*g] * sx + s_row[65 + 3*g] * sy + s_row[66 + 3*g] * sz) * inv_s3;
    s[9] = (s_row[88 + 3*g] * sx + s_row[89 + 3*g] * sy + s_row[90 + 3*g] * sz) * inv_s3;

    float ax = 0.f, ay = 0.f, az = 0.f, aw = 0.f;
    #pragma unroll
    for (int k = 0; k < 10; ++k) {
        ax += w[k].x * s[k]; ay += w[k].y * s[k];
        az += w[k].z * s[k]; aw += w[k].w * s[k];
    }
    #pragma unroll
    for (int m = 8; m <= 32; m <<= 1) {
        ax += __shfl_xor(ax, m); ay += __shfl_xor(ay, m);
        az += __shfl_xor(az, m); aw += __shfl_xor(aw, m);
    }
    if (g == 0 && valid) {
        const float n = 0.11180339887498949f;  // 1/sqrt(80)
        float4 r; r.x = ax*n; r.y = ay*n; r.z = az*n; r.w = aw*n;
        *reinterpret_cast<float4*>(outr + 4*o4) = r;
    }
}

__device__ __forceinline__ void comp_y1o(const float* __restrict__ s_row, const float4 w[6],
                                         int l,
                                         float sh0, float sx, float sy, float sz,
                                         float* __restrict__ outr, bool valid) {
    const int o4 = l & 3;
    const int g  = l >> 2;
    const float inv_s2 = 0.7071067811865476f;
    float s0[6], s1[6], s2[6];
    #pragma unroll
    for (int k = 0; k < 4; ++k) {
        const float x = s_row[g + (k << 4)];
        s0[k] = x * sx; s1[k] = x * sy; s2[k] = x * sz;
    }
    s0[4] = s_row[64 + 3*g] * sh0;
    s1[4] = s_row[65 + 3*g] * sh0;
    s2[4] = s_row[66 + 3*g] * sh0;
    {
        const float e0 = s_row[112 + 3*g], e1 = s_row[113 + 3*g], e2 = s_row[114 + 3*g];
        s0[5] = (e1 * sz - e2 * sy) * inv_s2;
        s1[5] = (e2 * sx - e0 * sz) * inv_s2;
        s2[5] = (e0 * sy - e1 * sx) * inv_s2;
    }
    float a0x=0,a0y=0,a0z=0,a0w=0;
    float a1x=0,a1y=0,a1z=0,a1w=0;
    float a2x=0,a2y=0,a2z=0,a2w=0;
    #pragma unroll
    for (int k = 0; k < 6; ++k) {
        a0x += w[k].x*s0[k]; a0y += w[k].y*s0[k]; a0z += w[k].z*s0[k]; a0w += w[k].w*s0[k];
        a1x += w[k].x*s1[k]; a1y += w[k].y*s1[k]; a1z += w[k].z*s1[k]; a1w += w[k].w*s1[k];
        a2x += w[k].x*s2[k]; a2y += w[k].y*s2[k]; a2z += w[k].z*s2[k]; a2w += w[k].w*s2[k];
    }
    #pragma unroll
    for (int m = 4; m <= 32; m <<= 1) {
        a0x += __shfl_xor(a0x, m); a0y += __shfl_xor(a0y, m);
        a0z += __shfl_xor(a0z, m); a0w += __shfl_xor(a0w, m);
        a1x += __shfl_xor(a1x, m); a1y += __shfl_xor(a1y, m);
        a1z += __shfl_xor(a1z, m); a1w += __shfl_xor(a1w, m);
        a2x += __shfl_xor(a2x, m); a2y += __shfl_xor(a2y, m);
        a2z += __shfl_xor(a2z, m); a2w += __shfl_xor(a2w, m);
    }
    if (g == 0 && valid) {
        const float n = 0.10206207261596575f;  // 1/sqrt(96)
        const int ob = 4*o4;
        outr[64 + (ob+0)*3 + 0] = a0x*n; outr[64 + (ob+0)*3 + 1] = a1x*n; outr[64 + (ob+0)*3 + 2] = a2x*n;
        outr[64 + (ob+1)*3 + 0] = a0y*n; outr[64 + (ob+1)*3 + 1] = a1y*n; outr[64 + (ob+1)*3 + 2] = a2y*n;
        outr[64 + (ob+2)*3 + 0] = a0z*n; outr[64 + (ob+2)*3 + 1] = a1z*n; outr[64 + (ob+2)*3 + 2] = a2z*n;
        outr[64 + (ob+3)*3 + 0] = a0w*n; outr[64 + (ob+3)*3 + 1] = a1w*n; outr[64 + (ob+3)*3 + 2] = a2w*n;
    }
}

__device__ __forceinline__ void comp_y1eo(const float* __restrict__ s_row,
                                          const float4 wa[3], const float4 wb[2],
                                          int l,
                                          float sh0, float sx, float sy, float sz,
                                          float* __restrict__ outr, bool valid) {
    const int o4 = l & 3;
    const int g  = l >> 2;
    const float inv_s2 = 0.7071067811865476f;
    const float inv_s3 = 0.5773502691896258f;

    float s0[3], s1[3], s2[3];
    {
        const float o0 = s_row[64 + 3*g], o1 = s_row[65 + 3*g], o2 = s_row[66 + 3*g];
        s0[0] = (o1 * sz - o2 * sy) * inv_s2;
        s1[0] = (o2 * sx - o0 * sz) * inv_s2;
        s2[0] = (o0 * sy - o1 * sx) * inv_s2;
    }
    const float e0 = s_row[112 + 3*g], e1 = s_row[113 + 3*g], e2 = s_row[114 + 3*g];
    s0[1] = e0 * sh0; s1[1] = e1 * sh0; s2[1] = e2 * sh0;
    const float xo = s_row[160 + g];
    s0[2] = xo * sx; s1[2] = xo * sy; s2[2] = xo * sz;

    float a0x=0,a0y=0,a0z=0,a0w=0;
    float a1x=0,a1y=0,a1z=0,a1w=0;
    float a2x=0,a2y=0,a2z=0,a2w=0;
    #pragma unroll
    for (int k = 0; k < 3; ++k) {
        a0x += wa[k].x*s0[k]; a0y += wa[k].y*s0[k]; a0z += wa[k].z*s0[k]; a0w += wa[k].w*s0[k];
        a1x += wa[k].x*s1[k]; a1y += wa[k].y*s1[k]; a1z += wa[k].z*s1[k]; a1w += wa[k].w*s1[k];
        a2x += wa[k].x*s2[k]; a2y += wa[k].y*s2[k]; a2z += wa[k].z*s2[k]; a2w += wa[k].w*s2[k];
    }
    float sb0 = (e0 * sx + e1 * sy + e2 * sz) * inv_s3;
    float sb1 = xo * sh0;
    float bx = wb[0].x*sb0 + wb[1].x*sb1;
    float by = wb[0].y*sb0 + wb[1].y*sb1;
    float bz = wb[0].z*sb0 + wb[1].z*sb1;
    float bw = wb[0].w*sb0 + wb[1].w*sb1;

    #pragma unroll
    for (int m = 4; m <= 32; m <<= 1) {
        a0x += __shfl_xor(a0x, m); a0y += __shfl_xor(a0y, m);
        a0z += __shfl_xor(a0z, m); a0w += __shfl_xor(a0w, m);
        a1x += __shfl_xor(a1x, m); a1y += __shfl_xor(a1y, m);
        a1z += __shfl_xor(a1z, m); a1w += __shfl_xor(a1w, m);
        a2x += __shfl_xor(a2x, m); a2y += __shfl_xor(a2y, m);
        a2z += __shfl_xor(a2z, m); a2w += __shfl_xor(a2w, m);
        bx  += __shfl_xor(bx,  m); by  += __shfl_xor(by,  m);
        bz  += __shfl_xor(bz,  m); bw  += __shfl_xor(bw,  m);
    }
    if (g == 0 && valid) {
        const float n48 = 0.14433756729740643f;  // 1/sqrt(48)
        const int ob = 4*o4;
        outr[112 + (ob+0)*3 + 0] = a0x*n48; outr[112 + (ob+0)*3 + 1] = a1x*n48; outr[112 + (ob+0)*3 + 2] = a2x*n48;
        outr[112 + (ob+1)*3 + 0] = a0y*n48; outr[112 + (ob+1)*3 + 1] = a1y*n48; outr[112 + (ob+1)*3 + 2] = a2y*n48;
        outr[112 + (ob+2)*3 + 0] = a0z*n48; outr[112 + (ob+2)*3 + 1] = a1z*n48; outr[112 + (ob+2)*3 + 2] = a2z*n48;
        outr[112 + (ob+3)*3 + 0] = a0w*n48; outr[112 + (ob+3)*3 + 1] = a1w*n48; outr[112 + (ob+3)*3 + 2] = a2w*n48;

        const float n32 = 0.17677669529663687f;  // 1/sqrt(32)
        float4 r; r.x = bx*n32; r.y = by*n32; r.z = bz*n32; r.w = bw*n32;
        *reinterpret_cast<float4*>(outr + 160 + 4*o4) = r;
    }
}

// ---------------- kernel: 2 rows/block, role-swapped waves, NT weight stream ----------------

__global__ __launch_bounds__(256, 4)
void ftp_kernel(const float* __restrict__ in_,
                const float* __restrict__ sh,
                const float* __restrict__ weight,
                float* __restrict__ out,
                int E)
{
    __shared__ float s_in[4][2][192];

    const int bid = blockIdx.x;
    const int t = threadIdx.x;
    const int wave = t >> 6;
    const int l = t & 63;

    const int r0 = 2 * bid;
    const int r1 = 2 * bid + 1;
    const bool v1 = (r1 < E);
    const int r1c = v1 ? r1 : r0;   // clamped for safe loads

    const float* __restrict__ in0 = in_ + (size_t)r0 * IN_DIM;
    const float* __restrict__ in1 = in_ + (size_t)r1c * IN_DIM;
    const float* __restrict__ wr0 = weight + (size_t)r0 * W_NUMEL;
    const float* __restrict__ wr1 = weight + (size_t)r1c * W_NUMEL;
    float* __restrict__ out0 = out + (size_t)r0 * OUT_DIM;
    float* __restrict__ out1 = out + (size_t)r1c * OUT_DIM;

    // issue input-row loads first (6 scalar loads/lane, coalesced)
    const float a0 = in0[l];
    const float a1 = in0[64 + l];
    const float a2 = (l < 48) ? in0[128 + l] : 0.0f;
    const float b0 = in1[l];
    const float b1 = in1[64 + l];
    const float b2 = (l < 48) ? in1[128 + l] : 0.0f;

    // sh (wave-uniform scalar loads)
    const float* shr0 = sh + (size_t)r0 * 4;
    const float* shr1 = sh + (size_t)r1c * 4;
    const float p0 = shr0[0], px = shr0[1], py = shr0[2], pz = shr0[3];
    const float q0 = shr1[0], qx = shr1[1], qy = shr1[2], qz = shr1[3];

    float* sA = &s_in[wave][0][0];
    float* sB = &s_in[wave][1][0];

#define STAGE_AND_WAIT()                                        \
    do {                                                        \
        sA[l] = a0; sA[64 + l] = a1; if (l < 48) sA[128 + l] = a2; \
        sB[l] = b0; sB[64 + l] = b1; if (l < 48) sB[128 + l] = b2; \
        __builtin_amdgcn_wave_barrier();                        \
        asm volatile("s_waitcnt lgkmcnt(0)" ::: "memory");      \
        __builtin_amdgcn_sched_barrier(0);                      \
    } while (0)

    if (wave == 0) {
        float4 wA[10]; load_y0e(wr0, l, 0, wA);
        float4 wB[6];  load_y1o(wr1, l, wB);
        STAGE_AND_WAIT();
        comp_y0e(sA, wA, l, 0, p0, px, py, pz, out0, true);
        comp_y1o(sB, wB, l, q0, qx, qy, qz, out1, v1);
    } else if (wave == 1) {
        float4 wA[10]; load_y0e(wr0, l, 1, wA);
        float4 wa[3], wb[2]; load_y1eo(wr1, l, wa, wb);
        STAGE_AND_WAIT();
        comp_y0e(sA, wA, l, 1, p0, px, py, pz, out0, true);
        comp_y1eo(sB, wa, wb, l, q0, qx, qy, qz, out1, v1);
    } else if (wave == 2) {
        float4 wA[6];  load_y1o(wr0, l, wA);
        float4 wB[10]; load_y0e(wr1, l, 0, wB);
        STAGE_AND_WAIT();
        comp_y1o(sA, wA, l, p0, px, py, pz, out0, true);
        comp_y0e(sB, wB, l, 0, q0, qx, qy, qz, out1, v1);
    } else {
        float4 wa[3], wb[2]; load_y1eo(wr0, l, wa, wb);
        float4 wB[10]; load_y0e(wr1, l, 1, wB);
        STAGE_AND_WAIT();
        comp_y1eo(sA, wa, wb, l, p0, px, py, pz, out0, true);
        comp_y0e(sB, wB, l, 1, q0, qx, qy, qz, out1, v1);
    }
#undef STAGE_AND_WAIT
}

extern "C" void kernel_launch(void* const* d_in, const int* in_sizes, int n_in,
                              void* d_out, int out_size, void* d_ws, size_t ws_size,
                              hipStream_t stream) {
    const float* in_    = (const float*)d_in[0];
    const float* sh     = (const float*)d_in[1];
    const float* weight = (const float*)d_in[2];
    float* out = (float*)d_out;
    const int E = in_sizes[0] / IN_DIM;
    const int nblocks = (E + 1) / 2;

    ftp_kernel<<<nblocks, 256, 0, stream>>>(in_, sh, weight, out, E);
}